// Round 6
// baseline (319.832 us; speedup 1.0000x reference)
//
#include <hip/hip_runtime.h>
#include <hip/hip_bf16.h>
#include <stdint.h>

typedef __bf16 bf16_t;
typedef __bf16 bf16x2 __attribute__((ext_vector_type(2)));
typedef __bf16 bf16x4 __attribute__((ext_vector_type(4)));
typedef __bf16 bf16x8 __attribute__((ext_vector_type(8)));
typedef float f32x4 __attribute__((ext_vector_type(4)));

// Async global->LDS, 16B per lane. LDS dst is wave-uniform base + lane*16.
__device__ __forceinline__ void async_ld16(const bf16_t* g, bf16_t* lds) {
    __builtin_amdgcn_global_load_lds(
        (__attribute__((address_space(1))) void*)g,
        (__attribute__((address_space(3))) void*)lds,
        16, 0, 0);
}

__device__ __forceinline__ void wait_vm0() {
    asm volatile("s_waitcnt vmcnt(0)" ::: "memory");
}

// ---------------- X convert: fp32 -> bf16, ILP'd grid-stride -----------------
// R2 prep was 72.5us @ 2.2 TB/s, VALU 7%: latency-bound, not BW-bound. Fix is
// ILP (G7), not access-pattern: 4 independent stride-spaced float4 loads per
// iter (64B outstanding per thread). R1/R5 proved fusing this convert into the
// GEMM loses ~45us — the standalone streaming kernel is the right structure.
__global__ __launch_bounds__(256) void convert_x(
    const float* __restrict__ X, bf16_t* __restrict__ Xb, int n4)
{
    const int stride = gridDim.x * 256;
    int i = blockIdx.x * 256 + threadIdx.x;
    const int lim = n4 - 3 * stride;
    for (; i < lim; i += 4 * stride) {
        const float4 v0 = ((const float4*)X)[i];
        const float4 v1 = ((const float4*)X)[i + stride];
        const float4 v2 = ((const float4*)X)[i + 2 * stride];
        const float4 v3 = ((const float4*)X)[i + 3 * stride];
        bf16x4 o0 = { (bf16_t)v0.x, (bf16_t)v0.y, (bf16_t)v0.z, (bf16_t)v0.w };
        bf16x4 o1 = { (bf16_t)v1.x, (bf16_t)v1.y, (bf16_t)v1.z, (bf16_t)v1.w };
        bf16x4 o2 = { (bf16_t)v2.x, (bf16_t)v2.y, (bf16_t)v2.z, (bf16_t)v2.w };
        bf16x4 o3 = { (bf16_t)v3.x, (bf16_t)v3.y, (bf16_t)v3.z, (bf16_t)v3.w };
        ((bf16x4*)Xb)[i]              = o0;
        ((bf16x4*)Xb)[i + stride]     = o1;
        ((bf16x4*)Xb)[i + 2 * stride] = o2;
        ((bf16x4*)Xb)[i + 3 * stride] = o3;
    }
    for (; i < n4; i += stride) {
        const float4 v = ((const float4*)X)[i];
        bf16x4 o = { (bf16_t)v.x, (bf16_t)v.y, (bf16_t)v.z, (bf16_t)v.w };
        ((bf16x4*)Xb)[i] = o;
    }
}

// ---------------- weight transposes: 4 row-tiles per block -------------------
// Same proven 0-conflict 32x32 scheme as R2 (R3's 64x64 rework regressed with
// 876K conflict cycles — kept reverted). Batching 4 stacked row-tiles per block
// issues 32 independent loads before the single __syncthreads (vs 8), 4x
// latency amortization for these tiny latency-bound blocks.
__device__ __forceinline__ void transpose_tile4(
    const float* __restrict__ in, bf16_t* __restrict__ out,
    int R, int C, int Cp, int tileIdx, int tid, float (*tile)[32][33])
{
    const int tilesX = Cp / 32;
    const int c0 = (tileIdx % tilesX) * 32;
    const int r0 = (tileIdx / tilesX) * 128;   // 4 stacked 32-row tiles
    const int tx = tid & 31;
    const int ty = tid >> 5;   // 0..7
#pragma unroll
    for (int s = 0; s < 4; ++s)
#pragma unroll
        for (int i = 0; i < 32; i += 8) {
            int rr = r0 + s * 32 + ty + i, cc = c0 + tx;
            float v = 0.f;
            if (cc < C) v = in[(size_t)rr * C + cc];   // R tiles always in-bounds
            tile[s][ty + i][tx] = v;
        }
    __syncthreads();
    const int px = tid & 15;
    const int py = tid >> 4;   // 0..15
#pragma unroll
    for (int s = 0; s < 4; ++s)
#pragma unroll
        for (int i = 0; i < 32; i += 16) {
            int oc = c0 + py + i;              // output row (original column)
            int orr = r0 + s * 32 + px * 2;    // output col (original row), pair
            bf16x2 o = { (bf16_t)tile[s][px * 2][py + i],
                         (bf16_t)tile[s][px * 2 + 1][py + i] };
            *(bf16x2*)&out[(size_t)oc * R + orr] = o;
        }
}

__global__ void prep_w(const float* __restrict__ W1, bf16_t* __restrict__ W1T,
                       const float* __restrict__ W2, bf16_t* __restrict__ W2T,
                       const float* __restrict__ Wc, bf16_t* __restrict__ WcT,
                       int FEAT, int HID, int NC, int NCP, int t1, int t2)
{
    __shared__ float tile[4][32][33];
    int bid = blockIdx.x;
    int tid = threadIdx.x;
    if (bid < t1) { transpose_tile4(W1, W1T, FEAT, HID, HID, bid, tid, tile); return; }
    bid -= t1;
    if (bid < t2) { transpose_tile4(W2, W2T, HID, HID, HID, bid, tid, tile); return; }
    bid -= t2;
    transpose_tile4(Wc, WcT, HID, NC, NCP, bid, tid, tile);
}

// ---------------- GEMM 128x128, BK=64 + XOR swizzle, split-K, 2-phase --------
// A: [M][K] bf16. B: [N][K] bf16 (weights transposed). P: [S][M][N] fp32.
// R2-proven 2-phase double-buffer: issue tile t+1's global_load_lds BEFORE
// computing tile t; single vmcnt(0) + raw s_barrier at END of step. LDS XOR
// swizzle: staging fetches pre-swizzled global chunk (lane&7)^(row&7); frag
// reads apply ^(r&7). 0 conflicts measured.
// NEW (T1): XCD-keyed block decode. Linear dispatch id o round-robins XCDs;
// decoding bn = o%8 pins one bn per XCD, so the 4 s-chunks of that B-panel
// (3.2 MB) stay L2-resident (4 MB/XCD) across all 16 bm blocks reading them.
__global__ __launch_bounds__(256, 2) void gemm128_bk64(
    const bf16_t* __restrict__ A, const bf16_t* __restrict__ B,
    float* __restrict__ P, int M, int N, int K, int KC)
{
    __shared__ __align__(16) bf16_t Asm[2][128 * 64];
    __shared__ __align__(16) bf16_t Bsm[2][128 * 64];

    const int tid  = threadIdx.x;
    const int wave = tid >> 6;
    const int lane = tid & 63;

    // bijective decode of (bm, bn, s) from linear dispatch order, bn fastest
    const int o   = blockIdx.x + gridDim.x * (blockIdx.y + gridDim.y * blockIdx.z);
    const int bn  = o % gridDim.y;
    const int tmp = o / gridDim.y;
    const int bm  = tmp % gridDim.x;
    const int s   = tmp / gridDim.x;

    const int Koff = s * KC;
    const int Kc   = (K - Koff < KC) ? (K - Koff) : KC;   // multiple of 64
    const int nt   = Kc >> 6;

    const bf16_t* Ab = A + (size_t)bm * 128 * K + Koff;
    const bf16_t* Bb = B + (size_t)bn * 128 * K + Koff;

    const int sr = lane >> 3;
    const int sk = ((lane & 7) ^ (sr & 7)) * 8;

    const int wm = (wave >> 1) * 64;
    const int wn = (wave & 1) * 64;
    const int r  = lane & 15;
    const int q  = lane >> 4;

    f32x4 acc[4][4];
#pragma unroll
    for (int i = 0; i < 4; ++i)
#pragma unroll
        for (int j = 0; j < 4; ++j)
            acc[i][j] = f32x4{0.f, 0.f, 0.f, 0.f};

    auto issue = [&](int t, int buf) {
#pragma unroll
        for (int i = 0; i < 4; ++i) {
            const int rb = wave * 32 + i * 8;
            async_ld16(Ab + (size_t)(rb + sr) * K + (t * 64 + sk), &Asm[buf][rb * 64]);
            async_ld16(Bb + (size_t)(rb + sr) * K + (t * 64 + sk), &Bsm[buf][rb * 64]);
        }
    };

    issue(0, 0);
    wait_vm0();
    __builtin_amdgcn_s_barrier();

    int cur = 0;
    for (int t = 0; t < nt; ++t) {
        const bool more = (t + 1 < nt);
        if (more) issue(t + 1, cur ^ 1);   // in flight across compute

#pragma unroll
        for (int rnd = 0; rnd < 2; ++rnd) {
            bf16x8 af[4], bfr[4];
#pragma unroll
            for (int i = 0; i < 4; ++i)
                af[i] = *(const bf16x8*)&Asm[cur][(wm + i * 16 + r) * 64
                                                  + ((rnd * 4 + q) ^ (r & 7)) * 8];
#pragma unroll
            for (int j = 0; j < 4; ++j)
                bfr[j] = *(const bf16x8*)&Bsm[cur][(wn + j * 16 + r) * 64
                                                   + ((rnd * 4 + q) ^ (r & 7)) * 8];
#pragma unroll
            for (int i = 0; i < 4; ++i)
#pragma unroll
                for (int j = 0; j < 4; ++j)
                    acc[i][j] = __builtin_amdgcn_mfma_f32_16x16x32_bf16(af[i], bfr[j], acc[i][j], 0, 0, 0);
        }

        if (more) {
            wait_vm0();
            __builtin_amdgcn_s_barrier();
            cur ^= 1;
        }
    }

    float* Pb = P + ((size_t)s * M + (size_t)bm * 128) * N + (size_t)bn * 128;
    const int r4 = q * 4;
#pragma unroll
    for (int i = 0; i < 4; ++i)
#pragma unroll
        for (int j = 0; j < 4; ++j)
#pragma unroll
            for (int rg = 0; rg < 4; ++rg)
                Pb[(size_t)(wm + i * 16 + r4 + rg) * N + (wn + j * 16 + r)] = acc[i][j][rg];
}

// ---------------- GEMM 64x64, BK=64, full-K, fused bias(+ReLU) epilogue ------
template <bool RELU, typename OutT>
__global__ __launch_bounds__(256, 4) void gemm64_fused(
    const bf16_t* __restrict__ A, const bf16_t* __restrict__ B,
    const float* __restrict__ bias, OutT* __restrict__ out,
    int K, int Nout)
{
    __shared__ __align__(16) bf16_t Asm[2][64 * 64];
    __shared__ __align__(16) bf16_t Bsm[2][64 * 64];

    const int tid  = threadIdx.x;
    const int wave = tid >> 6;
    const int lane = tid & 63;
    const int bm = blockIdx.x, bn = blockIdx.y;

    const bf16_t* Ab = A + (size_t)bm * 64 * K;
    const bf16_t* Bb = B + (size_t)bn * 64 * K;

    const int sr = lane >> 3;
    const int sk = ((lane & 7) ^ (sr & 7)) * 8;

    const int wm = (wave >> 1) * 32;
    const int wn = (wave & 1) * 32;
    const int r  = lane & 15;
    const int q  = lane >> 4;
    const int nt = K >> 6;

    f32x4 acc[2][2];
#pragma unroll
    for (int i = 0; i < 2; ++i)
#pragma unroll
        for (int j = 0; j < 2; ++j)
            acc[i][j] = f32x4{0.f, 0.f, 0.f, 0.f};

    auto issue = [&](int t, int buf) {
#pragma unroll
        for (int i = 0; i < 2; ++i) {
            const int rb = wave * 16 + i * 8;
            async_ld16(Ab + (size_t)(rb + sr) * K + (t * 64 + sk), &Asm[buf][rb * 64]);
            async_ld16(Bb + (size_t)(rb + sr) * K + (t * 64 + sk), &Bsm[buf][rb * 64]);
        }
    };

    issue(0, 0);
    wait_vm0();
    __builtin_amdgcn_s_barrier();

    int cur = 0;
    for (int t = 0; t < nt; ++t) {
        const bool more = (t + 1 < nt);
        if (more) issue(t + 1, cur ^ 1);

#pragma unroll
        for (int rnd = 0; rnd < 2; ++rnd) {
            bf16x8 af[2], bfr[2];
#pragma unroll
            for (int i = 0; i < 2; ++i)
                af[i] = *(const bf16x8*)&Asm[cur][(wm + i * 16 + r) * 64
                                                  + ((rnd * 4 + q) ^ (r & 7)) * 8];
#pragma unroll
            for (int j = 0; j < 2; ++j)
                bfr[j] = *(const bf16x8*)&Bsm[cur][(wn + j * 16 + r) * 64
                                                   + ((rnd * 4 + q) ^ (r & 7)) * 8];
#pragma unroll
            for (int i = 0; i < 2; ++i)
#pragma unroll
                for (int j = 0; j < 2; ++j)
                    acc[i][j] = __builtin_amdgcn_mfma_f32_16x16x32_bf16(af[i], bfr[j], acc[i][j], 0, 0, 0);
        }

        if (more) {
            wait_vm0();
            __builtin_amdgcn_s_barrier();
            cur ^= 1;
        }
    }

    const int r4 = (lane >> 4) * 4;
    const int c  = lane & 15;
#pragma unroll
    for (int i = 0; i < 2; ++i)
#pragma unroll
        for (int j = 0; j < 2; ++j) {
            const int col = bn * 64 + wn + j * 16 + c;
            if (col < Nout) {
                const float bv = bias[col];
#pragma unroll
                for (int rg = 0; rg < 4; ++rg) {
                    const int row = bm * 64 + wm + i * 16 + r4 + rg;
                    float v = acc[i][j][rg] + bv;
                    if (RELU) v = fmaxf(v, 0.f);
                    out[(size_t)row * Nout + col] = (OutT)v;
                }
            }
        }
}

// ---------------- split-K reduction for layer 1 ----------------

template <int S>
__global__ void reduce_relu_bf16_k(const float* __restrict__ P, const float* __restrict__ bias,
                                   bf16_t* __restrict__ h, int MN, int Nm1) {
    int i4 = (blockIdx.x * 256 + threadIdx.x) * 4;
    if (i4 >= MN) return;
    int n = i4 & Nm1;
    float4 a = *(const float4*)(bias + n);
#pragma unroll
    for (int s = 0; s < S; ++s) {
        float4 p = *(const float4*)(P + (size_t)s * MN + i4);
        a.x += p.x; a.y += p.y; a.z += p.z; a.w += p.w;
    }
    a.x = fmaxf(a.x, 0.f); a.y = fmaxf(a.y, 0.f);
    a.z = fmaxf(a.z, 0.f); a.w = fmaxf(a.w, 0.f);
    bf16x4 o = { (bf16_t)a.x, (bf16_t)a.y, (bf16_t)a.z, (bf16_t)a.w };
    *(bf16x4*)(h + i4) = o;
}

// ---------------- launcher ----------------

extern "C" void kernel_launch(void* const* d_in, const int* in_sizes, int n_in,
                              void* d_out, int out_size, void* d_ws, size_t ws_size,
                              hipStream_t stream) {
    const float* X  = (const float*)d_in[0];
    // d_in[1] = batch_indices: group->MLP->ungroup is an identity permutation; unused.
    const float* W1 = (const float*)d_in[2];
    const float* b1 = (const float*)d_in[3];
    const float* W2 = (const float*)d_in[4];
    const float* b2 = (const float*)d_in[5];
    const float* Wc = (const float*)d_in[6];
    const float* bc = (const float*)d_in[7];
    float* out = (float*)d_out;

    const int M    = in_sizes[1];            // 2048
    const int FEAT = in_sizes[0] / M;        // 12544
    const int HID  = in_sizes[3];            // 1024
    const int NC   = in_sizes[7];            // 81
    const int NCP  = 128;                    // padded class dim for MFMA

    char* ws = (char*)d_ws;
    size_t off = 0;
    auto alloc = [&](size_t bytes) {
        char* p = ws + off;
        off += (bytes + 255) & ~(size_t)255;
        return p;
    };
    bf16_t* Xb  = (bf16_t*)alloc((size_t)M * FEAT * 2);
    bf16_t* W1T = (bf16_t*)alloc((size_t)FEAT * HID * 2);
    bf16_t* W2T = (bf16_t*)alloc((size_t)HID * HID * 2);
    bf16_t* WcT = (bf16_t*)alloc((size_t)NCP * HID * 2);
    bf16_t* h1  = (bf16_t*)alloc((size_t)M * HID * 2);
    bf16_t* h2  = (bf16_t*)alloc((size_t)M * HID * 2);
    float*  P   = (float*)(ws + off);

    size_t rem  = ws_size > off ? ws_size - off : 0;
    size_t perS = (size_t)M * HID * 4;
    int S1 = (rem >= 4 * perS) ? 4 : (rem >= 2 * perS) ? 2 : 1;
    int KC1 = ((FEAT / S1 + 63) / 64) * 64;  // 12544/4 = 3136, %64 == 0

    // 1a) X -> bf16 (ILP'd streaming convert)
    int n4 = (M * FEAT) / 4;
    convert_x<<<2048, 256, 0, stream>>>(X, Xb, n4);

    // 1b) W1/W2/Wc -> transposed bf16 [N][K], 4 row-tiles per block
    int t1 = (FEAT / 128) * (HID / 32);      // 98*32 = 3136
    int t2 = (HID / 128) * (HID / 32);       // 8*32  = 256
    int t3 = (HID / 128) * (NCP / 32);       // 8*4   = 32
    prep_w<<<t1 + t2 + t3, 256, 0, stream>>>(
        W1, W1T, W2, W2T, Wc, WcT, FEAT, HID, NC, NCP, t1, t2);

    // 2) layer 1: h1 = relu(X@W1 + b1), split-K, 2-phase dbuf, XCD-keyed decode
    gemm128_bk64<<<dim3(M / 128, HID / 128, S1), 256, 0, stream>>>(Xb, W1T, P, M, HID, FEAT, KC1);
    switch (S1) {
        case 4: reduce_relu_bf16_k<4><<<(M * HID / 4 + 255) / 256, 256, 0, stream>>>(P, b1, h1, M * HID, HID - 1); break;
        case 2: reduce_relu_bf16_k<2><<<(M * HID / 4 + 255) / 256, 256, 0, stream>>>(P, b1, h1, M * HID, HID - 1); break;
        default: reduce_relu_bf16_k<1><<<(M * HID / 4 + 255) / 256, 256, 0, stream>>>(P, b1, h1, M * HID, HID - 1); break;
    }

    // 3) layer 2: h2 = relu(h1@W2 + b2) — fused epilogue
    gemm64_fused<true, bf16_t><<<dim3(M / 64, HID / 64), 256, 0, stream>>>(h1, W2T, b2, h2, HID, HID);

    // 4) classifier: out = h2@Wc + bc — fused epilogue, fp32 out (n<81)
    gemm64_fused<false, float><<<dim3(M / 64, NCP / 64), 256, 0, stream>>>(h2, WcT, bc, out, HID, NC);
}

// Round 7
// 303.894 us; speedup vs baseline: 1.0524x; 1.0524x over previous
//
#include <hip/hip_runtime.h>
#include <hip/hip_bf16.h>
#include <stdint.h>

typedef __bf16 bf16_t;
typedef __bf16 bf16x2 __attribute__((ext_vector_type(2)));
typedef __bf16 bf16x4 __attribute__((ext_vector_type(4)));
typedef __bf16 bf16x8 __attribute__((ext_vector_type(8)));
typedef float f32x4 __attribute__((ext_vector_type(4)));

// Async global->LDS, 16B per lane. LDS dst is wave-uniform base + lane*16.
__device__ __forceinline__ void async_ld16(const bf16_t* g, bf16_t* lds) {
    __builtin_amdgcn_global_load_lds(
        (__attribute__((address_space(1))) void*)g,
        (__attribute__((address_space(3))) void*)lds,
        16, 0, 0);
}

__device__ __forceinline__ void wait_vm0() {
    asm volatile("s_waitcnt vmcnt(0)" ::: "memory");
}

// ---------------- fused prep: X convert (ILP) + weight transposes (tile4) ----
// One dispatch: convert blocks and transpose blocks run concurrently across
// CUs (single stream would serialize two launches). Convert: 4 independent
// stride-spaced float4 loads/iter (64B outstanding/thread — G7 ILP fix for the
// latency-bound stream; R2 monolith was 2.2 TB/s). Transpose: proven 0-conflict
// 32x32 scheme, 4 stacked row-tiles per block (32 independent loads before the
// single __syncthreads = 4x latency amortization). R3's 64x64 rework (876K
// conflict cycles) stays reverted.

__device__ __forceinline__ void transpose_tile4(
    const float* __restrict__ in, bf16_t* __restrict__ out,
    int R, int C, int Cp, int tileIdx, int tid, float (*tile)[32][33])
{
    const int tilesX = Cp / 32;
    const int c0 = (tileIdx % tilesX) * 32;
    const int r0 = (tileIdx / tilesX) * 128;   // 4 stacked 32-row tiles
    const int tx = tid & 31;
    const int ty = tid >> 5;   // 0..7
#pragma unroll
    for (int s = 0; s < 4; ++s)
#pragma unroll
        for (int i = 0; i < 32; i += 8) {
            int rr = r0 + s * 32 + ty + i, cc = c0 + tx;
            float v = 0.f;
            if (cc < C) v = in[(size_t)rr * C + cc];   // R tiles always in-bounds
            tile[s][ty + i][tx] = v;
        }
    __syncthreads();
    const int px = tid & 15;
    const int py = tid >> 4;   // 0..15
#pragma unroll
    for (int s = 0; s < 4; ++s)
#pragma unroll
        for (int i = 0; i < 32; i += 16) {
            int oc = c0 + py + i;              // output row (original column)
            int orr = r0 + s * 32 + px * 2;    // output col (original row), pair
            bf16x2 o = { (bf16_t)tile[s][px * 2][py + i],
                         (bf16_t)tile[s][px * 2 + 1][py + i] };
            *(bf16x2*)&out[(size_t)oc * R + orr] = o;
        }
}

__global__ void prep_all(const float* __restrict__ X, bf16_t* __restrict__ Xb, int n4,
                         const float* __restrict__ W1, bf16_t* __restrict__ W1T,
                         const float* __restrict__ W2, bf16_t* __restrict__ W2T,
                         const float* __restrict__ Wc, bf16_t* __restrict__ WcT,
                         int FEAT, int HID, int NC, int NCP,
                         int nCvt, int t1, int t2)
{
    __shared__ float tile[4][32][33];
    int bid = blockIdx.x;
    int tid = threadIdx.x;
    if (bid < nCvt) {
        const int stride = nCvt * 256;
        int i = bid * 256 + tid;
        const int lim = n4 - 3 * stride;
        for (; i < lim; i += 4 * stride) {
            const float4 v0 = ((const float4*)X)[i];
            const float4 v1 = ((const float4*)X)[i + stride];
            const float4 v2 = ((const float4*)X)[i + 2 * stride];
            const float4 v3 = ((const float4*)X)[i + 3 * stride];
            bf16x4 o0 = { (bf16_t)v0.x, (bf16_t)v0.y, (bf16_t)v0.z, (bf16_t)v0.w };
            bf16x4 o1 = { (bf16_t)v1.x, (bf16_t)v1.y, (bf16_t)v1.z, (bf16_t)v1.w };
            bf16x4 o2 = { (bf16_t)v2.x, (bf16_t)v2.y, (bf16_t)v2.z, (bf16_t)v2.w };
            bf16x4 o3 = { (bf16_t)v3.x, (bf16_t)v3.y, (bf16_t)v3.z, (bf16_t)v3.w };
            ((bf16x4*)Xb)[i]              = o0;
            ((bf16x4*)Xb)[i + stride]     = o1;
            ((bf16x4*)Xb)[i + 2 * stride] = o2;
            ((bf16x4*)Xb)[i + 3 * stride] = o3;
        }
        for (; i < n4; i += stride) {
            const float4 v = ((const float4*)X)[i];
            bf16x4 o = { (bf16_t)v.x, (bf16_t)v.y, (bf16_t)v.z, (bf16_t)v.w };
            ((bf16x4*)Xb)[i] = o;
        }
        return;
    }
    bid -= nCvt;
    if (bid < t1) { transpose_tile4(W1, W1T, FEAT, HID, HID, bid, tid, tile); return; }
    bid -= t1;
    if (bid < t2) { transpose_tile4(W2, W2T, HID, HID, HID, bid, tid, tile); return; }
    bid -= t2;
    transpose_tile4(Wc, WcT, HID, NC, NCP, bid, tid, tile);
}

// ---------------- GEMM 128x128, BK=64 + XOR swizzle, split-K, 2-phase --------
// A: [M][K] bf16. B: [N][K] bf16 (weights transposed). P: [S][M][N] fp32.
// R2-proven 2-phase double-buffer: issue tile t+1's global_load_lds BEFORE
// computing tile t; single vmcnt(0) + raw s_barrier at END of step. LDS XOR
// swizzle: staging fetches pre-swizzled global chunk (lane&7)^(row&7); frag
// reads apply ^(r&7). 0 conflicts measured.
// R6's XCD-keyed decode REVERTED: it raised FETCH 128->213 MB and cost ~5us
// (dispatch->XCD mapping assumption wrong / L3-fit working set — m160 regime).
// Plain blockIdx decode = the <72.4us R2 configuration.
__global__ __launch_bounds__(256, 2) void gemm128_bk64(
    const bf16_t* __restrict__ A, const bf16_t* __restrict__ B,
    float* __restrict__ P, int M, int N, int K, int KC)
{
    __shared__ __align__(16) bf16_t Asm[2][128 * 64];
    __shared__ __align__(16) bf16_t Bsm[2][128 * 64];

    const int tid  = threadIdx.x;
    const int wave = tid >> 6;
    const int lane = tid & 63;
    const int bm = blockIdx.x, bn = blockIdx.y, s = blockIdx.z;

    const int Koff = s * KC;
    const int Kc   = (K - Koff < KC) ? (K - Koff) : KC;   // multiple of 64
    const int nt   = Kc >> 6;

    const bf16_t* Ab = A + (size_t)bm * 128 * K + Koff;
    const bf16_t* Bb = B + (size_t)bn * 128 * K + Koff;

    const int sr = lane >> 3;
    const int sk = ((lane & 7) ^ (sr & 7)) * 8;

    const int wm = (wave >> 1) * 64;
    const int wn = (wave & 1) * 64;
    const int r  = lane & 15;
    const int q  = lane >> 4;

    f32x4 acc[4][4];
#pragma unroll
    for (int i = 0; i < 4; ++i)
#pragma unroll
        for (int j = 0; j < 4; ++j)
            acc[i][j] = f32x4{0.f, 0.f, 0.f, 0.f};

    auto issue = [&](int t, int buf) {
#pragma unroll
        for (int i = 0; i < 4; ++i) {
            const int rb = wave * 32 + i * 8;
            async_ld16(Ab + (size_t)(rb + sr) * K + (t * 64 + sk), &Asm[buf][rb * 64]);
            async_ld16(Bb + (size_t)(rb + sr) * K + (t * 64 + sk), &Bsm[buf][rb * 64]);
        }
    };

    issue(0, 0);
    wait_vm0();
    __builtin_amdgcn_s_barrier();

    int cur = 0;
    for (int t = 0; t < nt; ++t) {
        const bool more = (t + 1 < nt);
        if (more) issue(t + 1, cur ^ 1);   // in flight across compute

#pragma unroll
        for (int rnd = 0; rnd < 2; ++rnd) {
            bf16x8 af[4], bfr[4];
#pragma unroll
            for (int i = 0; i < 4; ++i)
                af[i] = *(const bf16x8*)&Asm[cur][(wm + i * 16 + r) * 64
                                                  + ((rnd * 4 + q) ^ (r & 7)) * 8];
#pragma unroll
            for (int j = 0; j < 4; ++j)
                bfr[j] = *(const bf16x8*)&Bsm[cur][(wn + j * 16 + r) * 64
                                                   + ((rnd * 4 + q) ^ (r & 7)) * 8];
#pragma unroll
            for (int i = 0; i < 4; ++i)
#pragma unroll
                for (int j = 0; j < 4; ++j)
                    acc[i][j] = __builtin_amdgcn_mfma_f32_16x16x32_bf16(af[i], bfr[j], acc[i][j], 0, 0, 0);
        }

        if (more) {
            wait_vm0();
            __builtin_amdgcn_s_barrier();
            cur ^= 1;
        }
    }

    float* Pb = P + ((size_t)s * M + (size_t)bm * 128) * N + (size_t)bn * 128;
    const int r4 = q * 4;
#pragma unroll
    for (int i = 0; i < 4; ++i)
#pragma unroll
        for (int j = 0; j < 4; ++j)
#pragma unroll
            for (int rg = 0; rg < 4; ++rg)
                Pb[(size_t)(wm + i * 16 + r4 + rg) * N + (wn + j * 16 + r)] = acc[i][j][rg];
}

// ---------------- GEMM 64x64, BK=64, full-K, fused bias(+ReLU) epilogue ------
template <bool RELU, typename OutT>
__global__ __launch_bounds__(256, 4) void gemm64_fused(
    const bf16_t* __restrict__ A, const bf16_t* __restrict__ B,
    const float* __restrict__ bias, OutT* __restrict__ out,
    int K, int Nout)
{
    __shared__ __align__(16) bf16_t Asm[2][64 * 64];
    __shared__ __align__(16) bf16_t Bsm[2][64 * 64];

    const int tid  = threadIdx.x;
    const int wave = tid >> 6;
    const int lane = tid & 63;
    const int bm = blockIdx.x, bn = blockIdx.y;

    const bf16_t* Ab = A + (size_t)bm * 64 * K;
    const bf16_t* Bb = B + (size_t)bn * 64 * K;

    const int sr = lane >> 3;
    const int sk = ((lane & 7) ^ (sr & 7)) * 8;

    const int wm = (wave >> 1) * 32;
    const int wn = (wave & 1) * 32;
    const int r  = lane & 15;
    const int q  = lane >> 4;
    const int nt = K >> 6;

    f32x4 acc[2][2];
#pragma unroll
    for (int i = 0; i < 2; ++i)
#pragma unroll
        for (int j = 0; j < 2; ++j)
            acc[i][j] = f32x4{0.f, 0.f, 0.f, 0.f};

    auto issue = [&](int t, int buf) {
#pragma unroll
        for (int i = 0; i < 2; ++i) {
            const int rb = wave * 16 + i * 8;
            async_ld16(Ab + (size_t)(rb + sr) * K + (t * 64 + sk), &Asm[buf][rb * 64]);
            async_ld16(Bb + (size_t)(rb + sr) * K + (t * 64 + sk), &Bsm[buf][rb * 64]);
        }
    };

    issue(0, 0);
    wait_vm0();
    __builtin_amdgcn_s_barrier();

    int cur = 0;
    for (int t = 0; t < nt; ++t) {
        const bool more = (t + 1 < nt);
        if (more) issue(t + 1, cur ^ 1);

#pragma unroll
        for (int rnd = 0; rnd < 2; ++rnd) {
            bf16x8 af[2], bfr[2];
#pragma unroll
            for (int i = 0; i < 2; ++i)
                af[i] = *(const bf16x8*)&Asm[cur][(wm + i * 16 + r) * 64
                                                  + ((rnd * 4 + q) ^ (r & 7)) * 8];
#pragma unroll
            for (int j = 0; j < 2; ++j)
                bfr[j] = *(const bf16x8*)&Bsm[cur][(wn + j * 16 + r) * 64
                                                   + ((rnd * 4 + q) ^ (r & 7)) * 8];
#pragma unroll
            for (int i = 0; i < 2; ++i)
#pragma unroll
                for (int j = 0; j < 2; ++j)
                    acc[i][j] = __builtin_amdgcn_mfma_f32_16x16x32_bf16(af[i], bfr[j], acc[i][j], 0, 0, 0);
        }

        if (more) {
            wait_vm0();
            __builtin_amdgcn_s_barrier();
            cur ^= 1;
        }
    }

    const int r4 = (lane >> 4) * 4;
    const int c  = lane & 15;
#pragma unroll
    for (int i = 0; i < 2; ++i)
#pragma unroll
        for (int j = 0; j < 2; ++j) {
            const int col = bn * 64 + wn + j * 16 + c;
            if (col < Nout) {
                const float bv = bias[col];
#pragma unroll
                for (int rg = 0; rg < 4; ++rg) {
                    const int row = bm * 64 + wm + i * 16 + r4 + rg;
                    float v = acc[i][j][rg] + bv;
                    if (RELU) v = fmaxf(v, 0.f);
                    out[(size_t)row * Nout + col] = (OutT)v;
                }
            }
        }
}

// ---------------- split-K reduction for layer 1 ----------------

template <int S>
__global__ void reduce_relu_bf16_k(const float* __restrict__ P, const float* __restrict__ bias,
                                   bf16_t* __restrict__ h, int MN, int Nm1) {
    int i4 = (blockIdx.x * 256 + threadIdx.x) * 4;
    if (i4 >= MN) return;
    int n = i4 & Nm1;
    float4 a = *(const float4*)(bias + n);
#pragma unroll
    for (int s = 0; s < S; ++s) {
        float4 p = *(const float4*)(P + (size_t)s * MN + i4);
        a.x += p.x; a.y += p.y; a.z += p.z; a.w += p.w;
    }
    a.x = fmaxf(a.x, 0.f); a.y = fmaxf(a.y, 0.f);
    a.z = fmaxf(a.z, 0.f); a.w = fmaxf(a.w, 0.f);
    bf16x4 o = { (bf16_t)a.x, (bf16_t)a.y, (bf16_t)a.z, (bf16_t)a.w };
    *(bf16x4*)(h + i4) = o;
}

// ---------------- launcher ----------------

extern "C" void kernel_launch(void* const* d_in, const int* in_sizes, int n_in,
                              void* d_out, int out_size, void* d_ws, size_t ws_size,
                              hipStream_t stream) {
    const float* X  = (const float*)d_in[0];
    // d_in[1] = batch_indices: group->MLP->ungroup is an identity permutation; unused.
    const float* W1 = (const float*)d_in[2];
    const float* b1 = (const float*)d_in[3];
    const float* W2 = (const float*)d_in[4];
    const float* b2 = (const float*)d_in[5];
    const float* Wc = (const float*)d_in[6];
    const float* bc = (const float*)d_in[7];
    float* out = (float*)d_out;

    const int M    = in_sizes[1];            // 2048
    const int FEAT = in_sizes[0] / M;        // 12544
    const int HID  = in_sizes[3];            // 1024
    const int NC   = in_sizes[7];            // 81
    const int NCP  = 128;                    // padded class dim for MFMA

    char* ws = (char*)d_ws;
    size_t off = 0;
    auto alloc = [&](size_t bytes) {
        char* p = ws + off;
        off += (bytes + 255) & ~(size_t)255;
        return p;
    };
    bf16_t* Xb  = (bf16_t*)alloc((size_t)M * FEAT * 2);
    bf16_t* W1T = (bf16_t*)alloc((size_t)FEAT * HID * 2);
    bf16_t* W2T = (bf16_t*)alloc((size_t)HID * HID * 2);
    bf16_t* WcT = (bf16_t*)alloc((size_t)NCP * HID * 2);
    bf16_t* h1  = (bf16_t*)alloc((size_t)M * HID * 2);
    bf16_t* h2  = (bf16_t*)alloc((size_t)M * HID * 2);
    float*  P   = (float*)(ws + off);

    size_t rem  = ws_size > off ? ws_size - off : 0;
    size_t perS = (size_t)M * HID * 4;
    int S1 = (rem >= 4 * perS) ? 4 : (rem >= 2 * perS) ? 2 : 1;
    int KC1 = ((FEAT / S1 + 63) / 64) * 64;  // 12544/4 = 3136, %64 == 0

    // 1) fused prep (single dispatch): X->bf16 (ILP'd), W->transposed bf16
    int n4   = (M * FEAT) / 4;
    int nCvt = 2048;
    int t1 = (FEAT / 128) * (HID / 32);      // 98*32 = 3136
    int t2 = (HID / 128) * (HID / 32);       // 8*32  = 256
    int t3 = (HID / 128) * (NCP / 32);       // 8*4   = 32
    prep_all<<<nCvt + t1 + t2 + t3, 256, 0, stream>>>(
        X, Xb, n4, W1, W1T, W2, W2T, Wc, WcT, FEAT, HID, NC, NCP, nCvt, t1, t2);

    // 2) layer 1: h1 = relu(X@W1 + b1), split-K, 2-phase dbuf
    gemm128_bk64<<<dim3(M / 128, HID / 128, S1), 256, 0, stream>>>(Xb, W1T, P, M, HID, FEAT, KC1);
    switch (S1) {
        case 4: reduce_relu_bf16_k<4><<<(M * HID / 4 + 255) / 256, 256, 0, stream>>>(P, b1, h1, M * HID, HID - 1); break;
        case 2: reduce_relu_bf16_k<2><<<(M * HID / 4 + 255) / 256, 256, 0, stream>>>(P, b1, h1, M * HID, HID - 1); break;
        default: reduce_relu_bf16_k<1><<<(M * HID / 4 + 255) / 256, 256, 0, stream>>>(P, b1, h1, M * HID, HID - 1); break;
    }

    // 3) layer 2: h2 = relu(h1@W2 + b2) — fused epilogue
    gemm64_fused<true, bf16_t><<<dim3(M / 64, HID / 64), 256, 0, stream>>>(h1, W2T, b2, h2, HID, HID);

    // 4) classifier: out = h2@Wc + bc — fused epilogue, fp32 out (n<81)
    gemm64_fused<false, float><<<dim3(M / 64, NCP / 64), 256, 0, stream>>>(h2, WcT, bc, out, HID, NC);
}

// Round 8
// 294.680 us; speedup vs baseline: 1.0854x; 1.0313x over previous
//
#include <hip/hip_runtime.h>
#include <hip/hip_bf16.h>
#include <stdint.h>

typedef __bf16 bf16_t;
typedef __bf16 bf16x2 __attribute__((ext_vector_type(2)));
typedef __bf16 bf16x4 __attribute__((ext_vector_type(4)));
typedef __bf16 bf16x8 __attribute__((ext_vector_type(8)));
typedef float f32x4 __attribute__((ext_vector_type(4)));

// Async global->LDS, 16B per lane. LDS dst is wave-uniform base + lane*16.
__device__ __forceinline__ void async_ld16(const bf16_t* g, bf16_t* lds) {
    __builtin_amdgcn_global_load_lds(
        (__attribute__((address_space(1))) void*)g,
        (__attribute__((address_space(3))) void*)lds,
        16, 0, 0);
}

__device__ __forceinline__ void wait_vm0() {
    asm volatile("s_waitcnt vmcnt(0)" ::: "memory");
}

// ---------------- fused prep: X convert + 3 weight transposes ----------------
// EXACT R2 code (72.5us measured). Session evidence: one-shot massive-grid
// convert + 32x32 transpose beats every restructuring tried (R3 64x64: 77.6us
// w/ 876K conflicts; R7 grid-stride ILP + tile4: 84us). Block turnover IS the
// pipelining for this latency-bound stream. Do not "improve" again.

__device__ __forceinline__ void transpose_tile(
    const float* __restrict__ in, bf16_t* __restrict__ out,
    int R, int C, int Cp, int tileIdx, int tid, float (*tile)[33])
{
    const int tilesX = Cp / 32;
    const int c0 = (tileIdx % tilesX) * 32;
    const int r0 = (tileIdx / tilesX) * 32;
    const int tx = tid & 31;
    const int ty = tid >> 5;   // 0..7
#pragma unroll
    for (int i = 0; i < 32; i += 8) {
        int rr = r0 + ty + i, cc = c0 + tx;
        float v = 0.f;
        if (cc < C) v = in[(size_t)rr * C + cc];   // R tiles always in-bounds
        tile[ty + i][tx] = v;
    }
    __syncthreads();
    // vectorized write-back: each thread stores bf16x2 (two consecutive R cols)
    const int px = tid & 15;
    const int py = tid >> 4;   // 0..15
#pragma unroll
    for (int i = 0; i < 32; i += 16) {
        int oc = c0 + py + i;         // output row (original column, zero-padded)
        int orr = r0 + px * 2;        // output col (original row), pair base
        bf16x2 o = { (bf16_t)tile[px * 2][py + i], (bf16_t)tile[px * 2 + 1][py + i] };
        *(bf16x2*)&out[(size_t)oc * R + orr] = o;
    }
}

__global__ void prep_all(const float* __restrict__ X, bf16_t* __restrict__ Xb, int n4,
                         const float* __restrict__ W1, bf16_t* __restrict__ W1T,
                         const float* __restrict__ W2, bf16_t* __restrict__ W2T,
                         const float* __restrict__ Wc, bf16_t* __restrict__ WcT,
                         int FEAT, int HID, int NC, int NCP,
                         int nCvt, int t1, int t2)
{
    __shared__ float tile[32][33];
    int bid = blockIdx.x;
    int tid = threadIdx.x;
    if (bid < nCvt) {
        int i = bid * 256 + tid;
        if (i < n4) {
            float4 v = ((const float4*)X)[i];
            bf16x4 o = { (bf16_t)v.x, (bf16_t)v.y, (bf16_t)v.z, (bf16_t)v.w };
            ((bf16x4*)Xb)[i] = o;
        }
        return;
    }
    bid -= nCvt;
    if (bid < t1) { transpose_tile(W1, W1T, FEAT, HID, HID, bid, tid, tile); return; }
    bid -= t1;
    if (bid < t2) { transpose_tile(W2, W2T, HID, HID, HID, bid, tid, tile); return; }
    bid -= t2;
    transpose_tile(Wc, WcT, HID, NC, NCP, bid, tid, tile);
}

// ---------------- GEMM 128x128, BK=64 + XOR swizzle, split-K, 2-phase --------
// EXACT R2 code (<72.4us measured). A: [M][K] bf16. B: [N][K] bf16. P: [S][M][N].
// 2-phase double-buffer: issue tile t+1's global_load_lds BEFORE computing tile
// t; single vmcnt(0) + raw s_barrier at END of step. LDS XOR swizzle: staging
// fetches pre-swizzled global chunk (lane&7)^(row&7); frag reads apply ^(r&7).
// 0 conflicts measured. R6's XCD-keyed decode stays reverted (FETCH 128->213MB).
__global__ __launch_bounds__(256, 2) void gemm128_bk64(
    const bf16_t* __restrict__ A, const bf16_t* __restrict__ B,
    float* __restrict__ P, int M, int N, int K, int KC)
{
    __shared__ __align__(16) bf16_t Asm[2][128 * 64];
    __shared__ __align__(16) bf16_t Bsm[2][128 * 64];

    const int tid  = threadIdx.x;
    const int wave = tid >> 6;
    const int lane = tid & 63;
    const int bm = blockIdx.x, bn = blockIdx.y, s = blockIdx.z;

    const int Koff = s * KC;
    const int Kc   = (K - Koff < KC) ? (K - Koff) : KC;   // multiple of 64
    const int nt   = Kc >> 6;

    const bf16_t* Ab = A + (size_t)bm * 128 * K + Koff;
    const bf16_t* Bb = B + (size_t)bn * 128 * K + Koff;

    const int sr = lane >> 3;
    const int sk = ((lane & 7) ^ (sr & 7)) * 8;

    const int wm = (wave >> 1) * 64;
    const int wn = (wave & 1) * 64;
    const int r  = lane & 15;
    const int q  = lane >> 4;

    f32x4 acc[4][4];
#pragma unroll
    for (int i = 0; i < 4; ++i)
#pragma unroll
        for (int j = 0; j < 4; ++j)
            acc[i][j] = f32x4{0.f, 0.f, 0.f, 0.f};

    auto issue = [&](int t, int buf) {
#pragma unroll
        for (int i = 0; i < 4; ++i) {
            const int rb = wave * 32 + i * 8;
            async_ld16(Ab + (size_t)(rb + sr) * K + (t * 64 + sk), &Asm[buf][rb * 64]);
            async_ld16(Bb + (size_t)(rb + sr) * K + (t * 64 + sk), &Bsm[buf][rb * 64]);
        }
    };

    issue(0, 0);
    wait_vm0();
    __builtin_amdgcn_s_barrier();

    int cur = 0;
    for (int t = 0; t < nt; ++t) {
        const bool more = (t + 1 < nt);
        if (more) issue(t + 1, cur ^ 1);   // in flight across compute

#pragma unroll
        for (int rnd = 0; rnd < 2; ++rnd) {
            bf16x8 af[4], bfr[4];
#pragma unroll
            for (int i = 0; i < 4; ++i)
                af[i] = *(const bf16x8*)&Asm[cur][(wm + i * 16 + r) * 64
                                                  + ((rnd * 4 + q) ^ (r & 7)) * 8];
#pragma unroll
            for (int j = 0; j < 4; ++j)
                bfr[j] = *(const bf16x8*)&Bsm[cur][(wn + j * 16 + r) * 64
                                                   + ((rnd * 4 + q) ^ (r & 7)) * 8];
#pragma unroll
            for (int i = 0; i < 4; ++i)
#pragma unroll
                for (int j = 0; j < 4; ++j)
                    acc[i][j] = __builtin_amdgcn_mfma_f32_16x16x32_bf16(af[i], bfr[j], acc[i][j], 0, 0, 0);
        }

        if (more) {
            wait_vm0();
            __builtin_amdgcn_s_barrier();
            cur ^= 1;
        }
    }

    float* Pb = P + ((size_t)s * M + (size_t)bm * 128) * N + (size_t)bn * 128;
    const int r4 = q * 4;
#pragma unroll
    for (int i = 0; i < 4; ++i)
#pragma unroll
        for (int j = 0; j < 4; ++j)
#pragma unroll
            for (int rg = 0; rg < 4; ++rg)
                Pb[(size_t)(wm + i * 16 + r4 + rg) * N + (wn + j * 16 + r)] = acc[i][j][rg];
}

// ---------------- GEMM 64x64, BK=64, full-K, fused bias(+ReLU) epilogue ------
// NEW (T4 pilot): 4-buffer LDS (64KB, still 2 blocks/CU) + depth-3 prefetch
// with hand-counted vmcnt. Steady state: compute tile t while tiles t+1,t+2,
// t+3 are in flight (12 loads); end-of-step vmcnt(8) releases only tile t+1's
// 4 loads -> ~0 exposed HBM latency per step (was a full vmcnt(0) drain).
// Buffer-reuse safety: iter t's issue targets buf (t+3)&3 == (t-1)&3, which
// all waves finished reading before the barrier that ended iter t-1.
// All branches block-uniform (nt is uniform).
template <bool RELU, typename OutT>
__global__ __launch_bounds__(256, 2) void gemm64_fused(
    const bf16_t* __restrict__ A, const bf16_t* __restrict__ B,
    const float* __restrict__ bias, OutT* __restrict__ out,
    int K, int Nout)
{
    __shared__ __align__(16) bf16_t Asm[4][64 * 64];
    __shared__ __align__(16) bf16_t Bsm[4][64 * 64];

    const int tid  = threadIdx.x;
    const int wave = tid >> 6;
    const int lane = tid & 63;
    const int bm = blockIdx.x, bn = blockIdx.y;

    const bf16_t* Ab = A + (size_t)bm * 64 * K;
    const bf16_t* Bb = B + (size_t)bn * 64 * K;

    const int sr = lane >> 3;
    const int sk = ((lane & 7) ^ (sr & 7)) * 8;

    const int wm = (wave >> 1) * 32;
    const int wn = (wave & 1) * 32;
    const int r  = lane & 15;
    const int q  = lane >> 4;
    const int nt = K >> 6;

    f32x4 acc[2][2];
#pragma unroll
    for (int i = 0; i < 2; ++i)
#pragma unroll
        for (int j = 0; j < 2; ++j)
            acc[i][j] = f32x4{0.f, 0.f, 0.f, 0.f};

    auto issue = [&](int t, int buf) {
#pragma unroll
        for (int i = 0; i < 2; ++i) {
            const int rb = wave * 16 + i * 8;
            async_ld16(Ab + (size_t)(rb + sr) * K + (t * 64 + sk), &Asm[buf][rb * 64]);
            async_ld16(Bb + (size_t)(rb + sr) * K + (t * 64 + sk), &Bsm[buf][rb * 64]);
        }
    };
    // counted waits: each tile = 4 gl_lds ops (2 per lambda call x A,B... 2+2=4).
    auto wait8 = [&]() { asm volatile("s_waitcnt vmcnt(8)" ::: "memory"); };
    auto wait4 = [&]() { asm volatile("s_waitcnt vmcnt(4)" ::: "memory"); };

    // prologue: fill pipeline 3 deep, then wait for tile 0 only
    issue(0, 0);
    if (nt > 1) issue(1, 1);
    if (nt > 2) issue(2, 2);
    {
        const int depth = (nt > 2) ? 3 : (nt > 1 ? 2 : 1);
        if (depth == 3) wait8();
        else if (depth == 2) wait4();
        else wait_vm0();
    }
    __builtin_amdgcn_s_barrier();

    for (int t = 0; t < nt; ++t) {
        if (t + 3 < nt) issue(t + 3, (t + 3) & 3);
        const int cur = t & 3;

#pragma unroll
        for (int rnd = 0; rnd < 2; ++rnd) {
            bf16x8 af[2], bfr[2];
#pragma unroll
            for (int i = 0; i < 2; ++i)
                af[i] = *(const bf16x8*)&Asm[cur][(wm + i * 16 + r) * 64
                                                  + ((rnd * 4 + q) ^ (r & 7)) * 8];
#pragma unroll
            for (int j = 0; j < 2; ++j)
                bfr[j] = *(const bf16x8*)&Bsm[cur][(wn + j * 16 + r) * 64
                                                   + ((rnd * 4 + q) ^ (r & 7)) * 8];
#pragma unroll
            for (int i = 0; i < 2; ++i)
#pragma unroll
                for (int j = 0; j < 2; ++j)
                    acc[i][j] = __builtin_amdgcn_mfma_f32_16x16x32_bf16(af[i], bfr[j], acc[i][j], 0, 0, 0);
        }

        if (t + 1 < nt) {
            const int rem = nt - 1 - t;      // tiles still outstanding (t+1..)
            if (rem >= 3) wait8();           // 12 in flight -> tile t+1 done
            else if (rem == 2) wait4();      // 8 in flight  -> tile t+1 done
            else wait_vm0();                 // 4 in flight  -> tile t+1 done
            __builtin_amdgcn_s_barrier();
        }
    }

    const int r4 = (lane >> 4) * 4;
    const int c  = lane & 15;
#pragma unroll
    for (int i = 0; i < 2; ++i)
#pragma unroll
        for (int j = 0; j < 2; ++j) {
            const int col = bn * 64 + wn + j * 16 + c;
            if (col < Nout) {
                const float bv = bias[col];
#pragma unroll
                for (int rg = 0; rg < 4; ++rg) {
                    const int row = bm * 64 + wm + i * 16 + r4 + rg;
                    float v = acc[i][j][rg] + bv;
                    if (RELU) v = fmaxf(v, 0.f);
                    out[(size_t)row * Nout + col] = (OutT)v;
                }
            }
        }
}

// ---------------- split-K reduction for layer 1 ----------------

template <int S>
__global__ void reduce_relu_bf16_k(const float* __restrict__ P, const float* __restrict__ bias,
                                   bf16_t* __restrict__ h, int MN, int Nm1) {
    int i4 = (blockIdx.x * 256 + threadIdx.x) * 4;
    if (i4 >= MN) return;
    int n = i4 & Nm1;
    float4 a = *(const float4*)(bias + n);
#pragma unroll
    for (int s = 0; s < S; ++s) {
        float4 p = *(const float4*)(P + (size_t)s * MN + i4);
        a.x += p.x; a.y += p.y; a.z += p.z; a.w += p.w;
    }
    a.x = fmaxf(a.x, 0.f); a.y = fmaxf(a.y, 0.f);
    a.z = fmaxf(a.z, 0.f); a.w = fmaxf(a.w, 0.f);
    bf16x4 o = { (bf16_t)a.x, (bf16_t)a.y, (bf16_t)a.z, (bf16_t)a.w };
    *(bf16x4*)(h + i4) = o;
}

// ---------------- launcher ----------------

extern "C" void kernel_launch(void* const* d_in, const int* in_sizes, int n_in,
                              void* d_out, int out_size, void* d_ws, size_t ws_size,
                              hipStream_t stream) {
    const float* X  = (const float*)d_in[0];
    // d_in[1] = batch_indices: group->MLP->ungroup is an identity permutation; unused.
    const float* W1 = (const float*)d_in[2];
    const float* b1 = (const float*)d_in[3];
    const float* W2 = (const float*)d_in[4];
    const float* b2 = (const float*)d_in[5];
    const float* Wc = (const float*)d_in[6];
    const float* bc = (const float*)d_in[7];
    float* out = (float*)d_out;

    const int M    = in_sizes[1];            // 2048
    const int FEAT = in_sizes[0] / M;        // 12544
    const int HID  = in_sizes[3];            // 1024
    const int NC   = in_sizes[7];            // 81
    const int NCP  = 128;                    // padded class dim for MFMA

    char* ws = (char*)d_ws;
    size_t off = 0;
    auto alloc = [&](size_t bytes) {
        char* p = ws + off;
        off += (bytes + 255) & ~(size_t)255;
        return p;
    };
    bf16_t* Xb  = (bf16_t*)alloc((size_t)M * FEAT * 2);
    bf16_t* W1T = (bf16_t*)alloc((size_t)FEAT * HID * 2);
    bf16_t* W2T = (bf16_t*)alloc((size_t)HID * HID * 2);
    bf16_t* WcT = (bf16_t*)alloc((size_t)NCP * HID * 2);
    bf16_t* h1  = (bf16_t*)alloc((size_t)M * HID * 2);
    bf16_t* h2  = (bf16_t*)alloc((size_t)M * HID * 2);
    float*  P   = (float*)(ws + off);

    size_t rem  = ws_size > off ? ws_size - off : 0;
    size_t perS = (size_t)M * HID * 4;
    int S1 = (rem >= 4 * perS) ? 4 : (rem >= 2 * perS) ? 2 : 1;
    int KC1 = ((FEAT / S1 + 63) / 64) * 64;  // 12544/4 = 3136, %64 == 0

    // 1) fused prep: X->bf16, W1/W2/Wc -> transposed bf16 [N][K]  (exact R2)
    int n4   = (M * FEAT) / 4;
    int nCvt = (n4 + 255) / 256;
    int t1 = (HID / 32) * (FEAT / 32);
    int t2 = (HID / 32) * (HID / 32);
    int t3 = (NCP / 32) * (HID / 32);
    prep_all<<<nCvt + t1 + t2 + t3, 256, 0, stream>>>(
        X, Xb, n4, W1, W1T, W2, W2T, Wc, WcT, FEAT, HID, NC, NCP, nCvt, t1, t2);

    // 2) layer 1: h1 = relu(X@W1 + b1), split-K, 2-phase dbuf  (exact R2)
    gemm128_bk64<<<dim3(M / 128, HID / 128, S1), 256, 0, stream>>>(Xb, W1T, P, M, HID, FEAT, KC1);
    switch (S1) {
        case 4: reduce_relu_bf16_k<4><<<(M * HID / 4 + 255) / 256, 256, 0, stream>>>(P, b1, h1, M * HID, HID - 1); break;
        case 2: reduce_relu_bf16_k<2><<<(M * HID / 4 + 255) / 256, 256, 0, stream>>>(P, b1, h1, M * HID, HID - 1); break;
        default: reduce_relu_bf16_k<1><<<(M * HID / 4 + 255) / 256, 256, 0, stream>>>(P, b1, h1, M * HID, HID - 1); break;
    }

    // 3) layer 2: h2 = relu(h1@W2 + b2) — fused epilogue, depth-3 pipeline
    gemm64_fused<true, bf16_t><<<dim3(M / 64, HID / 64), 256, 0, stream>>>(h1, W2T, b2, h2, HID, HID);

    // 4) classifier: out = h2@Wc + bc — fused epilogue, fp32 out (n<81)
    gemm64_fused<false, float><<<dim3(M / 64, NCP / 64), 256, 0, stream>>>(h2, WcT, bc, out, HID, NC);
}